// Round 1
// baseline (4384.308 us; speedup 1.0000x reference)
//
#include <hip/hip_runtime.h>

// Sparse 3D UNet forward (fp32, VALU implicit-GEMM).
// One templated conv kernel; 27-tap gather -> LDS (transposed) -> 4x4 micro-tile GEMM.
// EPI: 0 = relu(y*s+b); 1 = relu(y*s+b + skip); 2 = relu(y*s+b) + pair-reduce(cat).

template<int CIN_A, int CIN_B, int COUT, int EPI>
__global__ __launch_bounds__(256) void spconv(
    const float* __restrict__ inA,
    const float* __restrict__ inB,
    const int*   __restrict__ nbr,   // [N][27]
    const float* __restrict__ W,     // [27][CIN][COUT]
    const float* __restrict__ bn,    // [2][COUT] (scale,bias)
    const float* __restrict__ skip,  // EPI==1 residual
    float*       __restrict__ out,   // [N][COUT]
    int N)
{
    constexpr int CIN   = CIN_A + CIN_B;
    constexpr int COL_T = COUT / 4;        // threads along cols
    constexpr int ROW_T = 256 / COL_T;     // threads along rows
    constexpr int BM    = ROW_T * 4;       // rows per block
    constexpr int V     = CIN / 4;         // float4 per gathered row

    __shared__ int   s_nbr[BM * 27];
    __shared__ float s_G[CIN][BM];         // transposed gathered tile
    __shared__ float s_W[CIN * COUT];

    const int tid  = threadIdx.x;
    const int tx   = tid % COL_T;
    const int ty   = tid / COL_T;
    const int row0 = blockIdx.x * BM;

    // stage neighbor lists (coalesced)
    for (int e = tid; e < BM * 27; e += 256) {
        int r = row0 + e / 27;
        s_nbr[e] = (r < N) ? nbr[(size_t)row0 * 27 + e] : -1;
    }

    float acc[4][4];
    #pragma unroll
    for (int i = 0; i < 4; ++i)
        #pragma unroll
        for (int j = 0; j < 4; ++j) acc[i][j] = 0.f;

    for (int k = 0; k < 27; ++k) {
        __syncthreads();   // previous GEMM done before overwriting LDS
        // stage W[k] -> LDS (linear [ci][co])
        constexpr int WQ = CIN * COUT / 4;
        const float4* Wg = reinterpret_cast<const float4*>(W + (size_t)k * CIN * COUT);
        #pragma unroll 1
        for (int e = tid; e < WQ; e += 256)
            reinterpret_cast<float4*>(s_W)[e] = Wg[e];
        // gather BM rows, write transposed (lane==row -> conflict-free)
        #pragma unroll 1
        for (int e = tid; e < BM * V; e += 256) {
            int r  = e % BM;
            int c4 = e / BM;
            int idx = s_nbr[r * 27 + k];
            float4 v = make_float4(0.f, 0.f, 0.f, 0.f);
            if (idx >= 0) {
                if (CIN_B == 0 || c4 * 4 < CIN_A)
                    v = *reinterpret_cast<const float4*>(inA + (size_t)idx * CIN_A + c4 * 4);
                else
                    v = *reinterpret_cast<const float4*>(inB + (size_t)idx * CIN_B + c4 * 4 - CIN_A);
            }
            s_G[c4 * 4 + 0][r] = v.x;
            s_G[c4 * 4 + 1][r] = v.y;
            s_G[c4 * 4 + 2][r] = v.z;
            s_G[c4 * 4 + 3][r] = v.w;
        }
        __syncthreads();
        // 4x4 micro-tile GEMM over this tap
        #pragma unroll 16
        for (int ci = 0; ci < CIN; ++ci) {
            float4 g = *reinterpret_cast<const float4*>(&s_G[ci][ty * 4]);
            float4 w = *reinterpret_cast<const float4*>(&s_W[ci * COUT + tx * 4]);
            acc[0][0] += g.x * w.x; acc[0][1] += g.x * w.y; acc[0][2] += g.x * w.z; acc[0][3] += g.x * w.w;
            acc[1][0] += g.y * w.x; acc[1][1] += g.y * w.y; acc[1][2] += g.y * w.z; acc[1][3] += g.y * w.w;
            acc[2][0] += g.z * w.x; acc[2][1] += g.z * w.y; acc[2][2] += g.z * w.z; acc[2][3] += g.z * w.w;
            acc[3][0] += g.w * w.x; acc[3][1] += g.w * w.y; acc[3][2] += g.w * w.z; acc[3][3] += g.w * w.w;
        }
    }

    // epilogue
    const int co0 = tx * 4;
    float4 sc = *reinterpret_cast<const float4*>(bn + co0);
    float4 bi = *reinterpret_cast<const float4*>(bn + COUT + co0);
    #pragma unroll
    for (int i = 0; i < 4; ++i) {
        int r = row0 + ty * 4 + i;
        if (r >= N) break;
        float4 y;
        y.x = acc[i][0] * sc.x + bi.x;
        y.y = acc[i][1] * sc.y + bi.y;
        y.z = acc[i][2] * sc.z + bi.z;
        y.w = acc[i][3] * sc.w + bi.w;
        if (EPI == 1) {
            float4 s = *reinterpret_cast<const float4*>(skip + (size_t)r * COUT + co0);
            y.x += s.x; y.y += s.y; y.z += s.z; y.w += s.w;
        }
        y.x = fmaxf(y.x, 0.f); y.y = fmaxf(y.y, 0.f);
        y.z = fmaxf(y.z, 0.f); y.w = fmaxf(y.w, 0.f);
        if (EPI == 2) {
            // reduce(cat,COUT)[r][co] = cat[r][2co] + cat[r][2co+1]
            const float* rs = (2 * co0 < CIN_A)
                ? inA + (size_t)r * CIN_A + 2 * co0
                : inB + (size_t)r * CIN_B + 2 * co0 - CIN_A;
            float4 p0 = reinterpret_cast<const float4*>(rs)[0];
            float4 p1 = reinterpret_cast<const float4*>(rs)[1];
            y.x += p0.x + p0.y; y.y += p0.z + p0.w;
            y.z += p1.x + p1.y; y.w += p1.z + p1.w;
        }
        *reinterpret_cast<float4*>(out + (size_t)r * COUT + co0) = y;
    }
}

extern "C" void kernel_launch(void* const* d_in, const int* in_sizes, int n_in,
                              void* d_out, int out_size, void* d_ws, size_t ws_size,
                              hipStream_t stream)
{
    (void)n_in; (void)out_size; (void)ws_size;
    const float* vf     = (const float*)d_in[0];
    const float* Win    = (const float*)d_in[1];
    const float* W32    = (const float*)d_in[2];
    const float* W64    = (const float*)d_in[3];
    const float* Wd3    = (const float*)d_in[4];
    const float* W6432  = (const float*)d_in[5];
    const float* W12864 = (const float*)d_in[6];
    const float* bn32   = (const float*)d_in[7];
    const float* bn64   = (const float*)d_in[8];
    const int* nbr1  = (const int*)d_in[9];
    const int* nbr2  = (const int*)d_in[10];
    const int* nbr3  = (const int*)d_in[11];
    const int* nbr4  = (const int*)d_in[12];
    const int* nbrd2 = (const int*)d_in[13];
    const int* nbrd3 = (const int*)d_in[14];
    const int* nbrd4 = (const int*)d_in[15];
    const int* nbri4 = (const int*)d_in[16];
    const int* nbri3 = (const int*)d_in[17];
    const int* nbri2 = (const int*)d_in[18];

    const int N1 = in_sizes[9]  / 27;
    const int N2 = in_sizes[10] / 27;
    const int N3 = in_sizes[11] / 27;
    const int N4 = in_sizes[12] / 27;

    float* ws = (float*)d_ws;
    size_t off = 0;
    auto alloc = [&](size_t n) { float* p = ws + off; off += n; return p; };
    float* X1  = alloc((size_t)N1 * 32);
    float* TA  = alloc((size_t)N1 * 32);
    float* TA2 = alloc((size_t)N1 * 32);
    float* TU1 = alloc((size_t)N1 * 32);
    float* X2  = alloc((size_t)N2 * 32);
    float* TB2 = alloc((size_t)N2 * 32);
    float* TC2 = alloc((size_t)N2 * 32);
    float* TU2 = alloc((size_t)N2 * 32);
    float* X3  = alloc((size_t)N3 * 64);
    float* TB3 = alloc((size_t)N3 * 64);
    float* TC3 = alloc((size_t)N3 * 64);
    float* TU3 = alloc((size_t)N3 * 64);
    float* X4  = alloc((size_t)N4 * 64);
    float* TB4 = alloc((size_t)N4 * 64);
    float* TC4 = alloc((size_t)N4 * 64);
    float* OUT = (float*)d_out;

    auto G32 = [](int N){ return dim3((unsigned)((N + 127) / 128)); };
    auto G64 = [](int N){ return dim3((unsigned)((N + 63) / 64)); };

    const size_t S32 = 27*32*32, S64 = (size_t)27*64*64, S6432 = (size_t)27*64*32, S12864 = (size_t)27*128*64;

    // ---------------- encoder ----------------
    spconv<4,0,32,0><<<G32(N1),256,0,stream>>>(vf, nullptr, nbr1, Win, bn32+0*64, nullptr, TA, N1);
    spconv<32,0,32,0><<<G32(N1),256,0,stream>>>(TA, nullptr, nbr1, W32+0*S32, bn32+1*64, nullptr, X1, N1);
    spconv<32,0,32,0><<<G32(N2),256,0,stream>>>(X1, nullptr, nbrd2, W32+1*S32, bn32+2*64, nullptr, TB2, N2);
    spconv<32,0,32,0><<<G32(N2),256,0,stream>>>(TB2, nullptr, nbr2, W32+2*S32, bn32+3*64, nullptr, TC2, N2);
    spconv<32,0,32,0><<<G32(N2),256,0,stream>>>(TC2, nullptr, nbr2, W32+3*S32, bn32+4*64, nullptr, X2, N2);
    spconv<32,0,64,0><<<G64(N3),256,0,stream>>>(X2, nullptr, nbrd3, Wd3, bn64+0*128, nullptr, TB3, N3);
    spconv<64,0,64,0><<<G64(N3),256,0,stream>>>(TB3, nullptr, nbr3, W64+0*S64, bn64+1*128, nullptr, TC3, N3);
    spconv<64,0,64,0><<<G64(N3),256,0,stream>>>(TC3, nullptr, nbr3, W64+1*S64, bn64+2*128, nullptr, X3, N3);
    spconv<64,0,64,0><<<G64(N4),256,0,stream>>>(X3, nullptr, nbrd4, W64+2*S64, bn64+3*128, nullptr, TB4, N4);
    spconv<64,0,64,0><<<G64(N4),256,0,stream>>>(TB4, nullptr, nbr4, W64+3*S64, bn64+4*128, nullptr, TC4, N4);
    spconv<64,0,64,0><<<G64(N4),256,0,stream>>>(TC4, nullptr, nbr4, W64+4*S64, bn64+5*128, nullptr, X4, N4);
    // ---------------- bottleneck: basic + cat-block+reduce ----------------
    spconv<64,0,64,0><<<G64(N4),256,0,stream>>>(X4, nullptr, nbr4, W64+5*S64, bn64+6*128, nullptr, TB4, N4);
    spconv<64,0,64,1><<<G64(N4),256,0,stream>>>(TB4, nullptr, nbr4, W64+6*S64, bn64+7*128, X4, TC4, N4);
    spconv<64,64,64,2><<<G64(N4),256,0,stream>>>(X4, TC4, nbr4, W12864+0*S12864, bn64+11*128, nullptr, TB4, N4);
    // ---------------- decoder: level 4 -> 3 ----------------
    spconv<64,0,64,0><<<G64(N3),256,0,stream>>>(TB4, nullptr, nbri4, W64+7*S64, bn64+8*128, nullptr, TU3, N3);
    spconv<64,0,64,0><<<G64(N3),256,0,stream>>>(X3, nullptr, nbr3, W64+8*S64, bn64+9*128, nullptr, TB3, N3);
    spconv<64,0,64,1><<<G64(N3),256,0,stream>>>(TB3, nullptr, nbr3, W64+9*S64, bn64+10*128, X3, TC3, N3);
    spconv<64,64,64,2><<<G64(N3),256,0,stream>>>(TU3, TC3, nbr3, W12864+1*S12864, bn64+12*128, nullptr, TB3, N3);
    // ---------------- decoder: level 3 -> 2 ----------------
    spconv<64,0,32,0><<<G32(N2),256,0,stream>>>(TB3, nullptr, nbri3, W6432+0*S6432, bn32+11*64, nullptr, TU2, N2);
    spconv<32,0,32,0><<<G32(N2),256,0,stream>>>(X2, nullptr, nbr2, W32+4*S32, bn32+5*64, nullptr, TB2, N2);
    spconv<32,0,32,1><<<G32(N2),256,0,stream>>>(TB2, nullptr, nbr2, W32+5*S32, bn32+6*64, X2, TC2, N2);
    spconv<32,32,32,2><<<G32(N2),256,0,stream>>>(TU2, TC2, nbr2, W6432+1*S6432, bn32+12*64, nullptr, TB2, N2);
    // ---------------- decoder: level 2 -> 1 ----------------
    spconv<32,0,32,0><<<G32(N1),256,0,stream>>>(TB2, nullptr, nbri2, W32+6*S32, bn32+7*64, nullptr, TU1, N1);
    spconv<32,0,32,0><<<G32(N1),256,0,stream>>>(X1, nullptr, nbr1, W32+7*S32, bn32+8*64, nullptr, TA, N1);
    spconv<32,0,32,1><<<G32(N1),256,0,stream>>>(TA, nullptr, nbr1, W32+8*S32, bn32+9*64, X1, TA2, N1);
    spconv<32,32,32,2><<<G32(N1),256,0,stream>>>(TU1, TA2, nbr1, W6432+2*S6432, bn32+13*64, nullptr, TA, N1);
    // ---------------- head ----------------
    spconv<32,0,32,0><<<G32(N1),256,0,stream>>>(TA, nullptr, nbr1, W32+9*S32, bn32+10*64, nullptr, OUT, N1);
}

// Round 2
// 4097.886 us; speedup vs baseline: 1.0699x; 1.0699x over previous
//
#include <hip/hip_runtime.h>

// Sparse 3D UNet forward (fp32, VALU implicit-GEMM).
// Round 2: split-K tap groups (fill the GPU), register-staged tap pipeline
// (overlap gather latency with GEMM), bijective XCD-aware block swizzle.

template<int CIN_A, int CIN_B, int COUT, int EPI, bool SPLIT>
__global__ __launch_bounds__(256) void spconv(
    const float* __restrict__ inA,
    const float* __restrict__ inB,
    const int*   __restrict__ nbr,   // [N][27]
    const float* __restrict__ W,     // [27][CIN][COUT]
    const float* __restrict__ bn,    // [2][COUT]
    const float* __restrict__ skip,  // EPI==1 residual
    float*       __restrict__ out,   // [N][COUT] (non-split)
    float*       __restrict__ pout,  // [KS][N][COUT] partials (split)
    int N, int KS)
{
    constexpr int CIN   = CIN_A + CIN_B;
    constexpr int BM    = (COUT == 32) ? 128 : 64;
    constexpr int COL_T = COUT / 4;
    constexpr int ROW_T = 256 / COL_T;
    static_assert(ROW_T * 4 == BM, "tile mismatch");
    constexpr int V     = CIN / 4;
    constexpr int GTOT  = BM * V;
    constexpr int GPT   = (GTOT + 255) / 256;
    constexpr int CSTR  = 256 / BM;
    constexpr int WTOT  = CIN * COUT / 4;
    constexpr int WPT   = (WTOT + 255) / 256;

    __shared__ int   s_nbr[BM * 27];
    __shared__ float s_G[CIN][BM];
    __shared__ float s_W[CIN * COUT];

    const int tid = threadIdx.x;
    const int tx  = tid % COL_T;
    const int ty  = tid / COL_T;

    // bijective XCD-aware swizzle (m204): same-XCD blocks get contiguous ids
    unsigned nwg = gridDim.x;
    unsigned q8 = nwg / 8u, r8 = nwg % 8u;
    unsigned xcd = blockIdx.x % 8u, sub = blockIdx.x / 8u;
    unsigned id = (xcd < r8 ? xcd * (q8 + 1u) : r8 * (q8 + 1u) + (xcd - r8) * q8) + sub;

    int rb, k0, k1, kg;
    if (SPLIT) {
        kg = (int)(id % (unsigned)KS);
        rb = (int)(id / (unsigned)KS);
        int kper = 27 / KS;          // KS in {3,9} divides 27
        k0 = kg * kper; k1 = k0 + kper;
    } else {
        kg = 0; rb = (int)id; k0 = 0; k1 = 27;
    }
    const int row0 = rb * BM;

    for (int e = tid; e < BM * 27; e += 256) {
        int rr = row0 + e / 27;
        s_nbr[e] = (rr < N) ? nbr[(size_t)row0 * 27 + e] : -1;
    }
    __syncthreads();

    const int gr  = tid % BM;   // gather row handled by this thread
    const int gc0 = tid / BM;   // first float4-column
    float4 gv[GPT];
    float4 wv[WPT];

    auto load_tap = [&](int k) {
        int idx = s_nbr[gr * 27 + k];
        #pragma unroll
        for (int j = 0; j < GPT; ++j) {
            int e = tid + j * 256;
            if ((GTOT % 256 == 0) || e < GTOT) {
                int c4 = gc0 + j * CSTR;
                float4 v = make_float4(0.f, 0.f, 0.f, 0.f);
                if (idx >= 0) {
                    if (CIN_B == 0 || c4 * 4 < CIN_A)
                        v = *(const float4*)(inA + (size_t)idx * CIN_A + c4 * 4);
                    else
                        v = *(const float4*)(inB + (size_t)idx * CIN_B + c4 * 4 - CIN_A);
                }
                gv[j] = v;
            }
        }
        const float4* Wg = (const float4*)(W + (size_t)k * CIN * COUT);
        #pragma unroll
        for (int j = 0; j < WPT; ++j) {
            int e = tid + j * 256;
            if ((WTOT % 256 == 0) || e < WTOT) wv[j] = Wg[e];
        }
    };

    auto store_tap = [&]() {
        #pragma unroll
        for (int j = 0; j < GPT; ++j) {
            int e = tid + j * 256;
            if ((GTOT % 256 == 0) || e < GTOT) {
                int c4 = gc0 + j * CSTR;
                s_G[c4 * 4 + 0][gr] = gv[j].x;
                s_G[c4 * 4 + 1][gr] = gv[j].y;
                s_G[c4 * 4 + 2][gr] = gv[j].z;
                s_G[c4 * 4 + 3][gr] = gv[j].w;
            }
        }
        #pragma unroll
        for (int j = 0; j < WPT; ++j) {
            int e = tid + j * 256;
            if ((WTOT % 256 == 0) || e < WTOT) ((float4*)s_W)[e] = wv[j];
        }
    };

    float acc[4][4] = {};
    load_tap(k0);

    for (int k = k0; k < k1; ++k) {
        __syncthreads();                 // prev GEMM done with LDS
        store_tap();
        __syncthreads();                 // tile ready
        if (k + 1 < k1) load_tap(k + 1); // prefetch next tap under the GEMM
        #pragma unroll 16
        for (int ci = 0; ci < CIN; ++ci) {
            float4 g = *(const float4*)&s_G[ci][ty * 4];
            float4 w = *(const float4*)&s_W[ci * COUT + tx * 4];
            acc[0][0] += g.x * w.x; acc[0][1] += g.x * w.y; acc[0][2] += g.x * w.z; acc[0][3] += g.x * w.w;
            acc[1][0] += g.y * w.x; acc[1][1] += g.y * w.y; acc[1][2] += g.y * w.z; acc[1][3] += g.y * w.w;
            acc[2][0] += g.z * w.x; acc[2][1] += g.z * w.y; acc[2][2] += g.z * w.z; acc[2][3] += g.z * w.w;
            acc[3][0] += g.w * w.x; acc[3][1] += g.w * w.y; acc[3][2] += g.w * w.z; acc[3][3] += g.w * w.w;
        }
    }

    const int co0 = tx * 4;
    if (SPLIT) {
        #pragma unroll
        for (int i = 0; i < 4; ++i) {
            int rr = row0 + ty * 4 + i;
            if (rr < N) {
                float4 y = make_float4(acc[i][0], acc[i][1], acc[i][2], acc[i][3]);
                *(float4*)(pout + ((size_t)kg * N + rr) * COUT + co0) = y;
            }
        }
    } else {
        float4 sc = *(const float4*)(bn + co0);
        float4 bi = *(const float4*)(bn + COUT + co0);
        #pragma unroll
        for (int i = 0; i < 4; ++i) {
            int rr = row0 + ty * 4 + i;
            if (rr >= N) break;
            float4 y;
            y.x = acc[i][0] * sc.x + bi.x;
            y.y = acc[i][1] * sc.y + bi.y;
            y.z = acc[i][2] * sc.z + bi.z;
            y.w = acc[i][3] * sc.w + bi.w;
            if (EPI == 1) {
                float4 s = *(const float4*)(skip + (size_t)rr * COUT + co0);
                y.x += s.x; y.y += s.y; y.z += s.z; y.w += s.w;
            }
            y.x = fmaxf(y.x, 0.f); y.y = fmaxf(y.y, 0.f);
            y.z = fmaxf(y.z, 0.f); y.w = fmaxf(y.w, 0.f);
            if (EPI == 2) {
                const float* rs = (2 * co0 < CIN_A)
                    ? inA + (size_t)rr * CIN_A + 2 * co0
                    : inB + (size_t)rr * CIN_B + 2 * co0 - CIN_A;
                float4 p0 = ((const float4*)rs)[0];
                float4 p1 = ((const float4*)rs)[1];
                y.x += p0.x + p0.y; y.y += p0.z + p0.w;
                y.z += p1.x + p1.y; y.w += p1.z + p1.w;
            }
            *(float4*)(out + (size_t)rr * COUT + co0) = y;
        }
    }
}

// Sum split-K partials + BN/ReLU/skip/pair-reduce epilogue.
template<int CIN_A, int CIN_B, int COUT, int EPI>
__global__ __launch_bounds__(256) void epi_k(
    const float* __restrict__ P, int KS,
    const float* __restrict__ bn,
    const float* __restrict__ skip,
    const float* __restrict__ inA,
    const float* __restrict__ inB,
    float* __restrict__ out, int N)
{
    int t = blockIdx.x * 256 + threadIdx.x;
    int total = N * (COUT / 4);
    if (t >= total) return;
    int r   = t / (COUT / 4);
    int co0 = (t % (COUT / 4)) * 4;

    float4 y = make_float4(0.f, 0.f, 0.f, 0.f);
    for (int kg = 0; kg < KS; ++kg) {
        float4 p = *(const float4*)(P + ((size_t)kg * N + r) * COUT + co0);
        y.x += p.x; y.y += p.y; y.z += p.z; y.w += p.w;
    }
    float4 sc = *(const float4*)(bn + co0);
    float4 bi = *(const float4*)(bn + COUT + co0);
    y.x = y.x * sc.x + bi.x; y.y = y.y * sc.y + bi.y;
    y.z = y.z * sc.z + bi.z; y.w = y.w * sc.w + bi.w;
    if (EPI == 1) {
        float4 s = *(const float4*)(skip + (size_t)r * COUT + co0);
        y.x += s.x; y.y += s.y; y.z += s.z; y.w += s.w;
    }
    y.x = fmaxf(y.x, 0.f); y.y = fmaxf(y.y, 0.f);
    y.z = fmaxf(y.z, 0.f); y.w = fmaxf(y.w, 0.f);
    if (EPI == 2) {
        const float* rs = (2 * co0 < CIN_A)
            ? inA + (size_t)r * CIN_A + 2 * co0
            : inB + (size_t)r * CIN_B + 2 * co0 - CIN_A;
        float4 p0 = ((const float4*)rs)[0];
        float4 p1 = ((const float4*)rs)[1];
        y.x += p0.x + p0.y; y.y += p0.z + p0.w;
        y.z += p1.x + p1.y; y.w += p1.z + p1.w;
    }
    *(float4*)(out + (size_t)r * COUT + co0) = y;
}

static inline int ksel(int nblk) {
    return nblk >= 512 ? 1 : (nblk >= 170 ? 3 : 9);
}

extern "C" void kernel_launch(void* const* d_in, const int* in_sizes, int n_in,
                              void* d_out, int out_size, void* d_ws, size_t ws_size,
                              hipStream_t stream)
{
    (void)n_in; (void)out_size; (void)ws_size;
    const float* vf     = (const float*)d_in[0];
    const float* Win    = (const float*)d_in[1];
    const float* W32    = (const float*)d_in[2];
    const float* W64    = (const float*)d_in[3];
    const float* Wd3    = (const float*)d_in[4];
    const float* W6432  = (const float*)d_in[5];
    const float* W12864 = (const float*)d_in[6];
    const float* bn32   = (const float*)d_in[7];
    const float* bn64   = (const float*)d_in[8];
    const int* nbr1  = (const int*)d_in[9];
    const int* nbr2  = (const int*)d_in[10];
    const int* nbr3  = (const int*)d_in[11];
    const int* nbr4  = (const int*)d_in[12];
    const int* nbrd2 = (const int*)d_in[13];
    const int* nbrd3 = (const int*)d_in[14];
    const int* nbrd4 = (const int*)d_in[15];
    const int* nbri4 = (const int*)d_in[16];
    const int* nbri3 = (const int*)d_in[17];
    const int* nbri2 = (const int*)d_in[18];

    const int N1 = in_sizes[9]  / 27;
    const int N2 = in_sizes[10] / 27;
    const int N3 = in_sizes[11] / 27;
    const int N4 = in_sizes[12] / 27;

    float* ws = (float*)d_ws;
    size_t off = 0;
    auto alloc = [&](size_t n) { float* p = ws + off; off += n; return p; };
    float* X1  = alloc((size_t)N1 * 32);
    float* TA  = alloc((size_t)N1 * 32);
    float* TA2 = alloc((size_t)N1 * 32);
    float* TU1 = alloc((size_t)N1 * 32);
    float* X2  = alloc((size_t)N2 * 32);
    float* TB2 = alloc((size_t)N2 * 32);
    float* TC2 = alloc((size_t)N2 * 32);
    float* TU2 = alloc((size_t)N2 * 32);
    float* X3  = alloc((size_t)N3 * 64);
    float* TB3 = alloc((size_t)N3 * 64);
    float* TC3 = alloc((size_t)N3 * 64);
    float* TU3 = alloc((size_t)N3 * 64);
    float* X4  = alloc((size_t)N4 * 64);
    float* TB4 = alloc((size_t)N4 * 64);
    float* TC4 = alloc((size_t)N4 * 64);
    float* OUT = (float*)d_out;

    // shared split-K partial buffer (max over all split convs)
    auto pneed = [&](int N, int BM, int CO) -> size_t {
        int nb = (N + BM - 1) / BM; int ks = ksel(nb);
        return ks > 1 ? (size_t)ks * N * CO : 0;
    };
    size_t maxP = 0;
    size_t c;
    c = pneed(N1, 128, 32); if (c > maxP) maxP = c;
    c = pneed(N2, 128, 32); if (c > maxP) maxP = c;
    c = pneed(N3,  64, 64); if (c > maxP) maxP = c;
    c = pneed(N4,  64, 64); if (c > maxP) maxP = c;
    float* P = alloc(maxP);

    const size_t S32 = 27*32*32, S64 = (size_t)27*64*64, S6432 = (size_t)27*64*32, S12864 = (size_t)27*128*64;

#define CONV(CA, CB, CO, EP, pA, pB, pN, pW, pBN, pS, pO, NN) do {                      \
        constexpr int BM_ = ((CO) == 32) ? 128 : 64;                                    \
        int nblk_ = ((NN) + BM_ - 1) / BM_;                                             \
        int ks_ = ksel(nblk_);                                                          \
        if (ks_ == 1) {                                                                 \
            spconv<CA, CB, CO, EP, false><<<dim3((unsigned)nblk_), 256, 0, stream>>>(   \
                pA, pB, pN, pW, pBN, pS, pO, nullptr, NN, 1);                           \
        } else {                                                                        \
            spconv<CA, CB, CO, EP, true><<<dim3((unsigned)(nblk_ * ks_)), 256, 0, stream>>>( \
                pA, pB, pN, pW, pBN, pS, nullptr, P, NN, ks_);                          \
            int tot4_ = (NN) * ((CO) / 4);                                              \
            epi_k<CA, CB, CO, EP><<<dim3((unsigned)((tot4_ + 255) / 256)), 256, 0, stream>>>( \
                P, ks_, pBN, pS, pA, pB, pO, NN);                                       \
        }                                                                               \
    } while (0)

    // ---------------- encoder ----------------
    CONV(4,0,32,0,  vf,  nullptr, nbr1,  Win,         bn32+0*64,  nullptr, TA,  N1);
    CONV(32,0,32,0, TA,  nullptr, nbr1,  W32+0*S32,   bn32+1*64,  nullptr, X1,  N1);
    CONV(32,0,32,0, X1,  nullptr, nbrd2, W32+1*S32,   bn32+2*64,  nullptr, TB2, N2);
    CONV(32,0,32,0, TB2, nullptr, nbr2,  W32+2*S32,   bn32+3*64,  nullptr, TC2, N2);
    CONV(32,0,32,0, TC2, nullptr, nbr2,  W32+3*S32,   bn32+4*64,  nullptr, X2,  N2);
    CONV(32,0,64,0, X2,  nullptr, nbrd3, Wd3,         bn64+0*128, nullptr, TB3, N3);
    CONV(64,0,64,0, TB3, nullptr, nbr3,  W64+0*S64,   bn64+1*128, nullptr, TC3, N3);
    CONV(64,0,64,0, TC3, nullptr, nbr3,  W64+1*S64,   bn64+2*128, nullptr, X3,  N3);
    CONV(64,0,64,0, X3,  nullptr, nbrd4, W64+2*S64,   bn64+3*128, nullptr, TB4, N4);
    CONV(64,0,64,0, TB4, nullptr, nbr4,  W64+3*S64,   bn64+4*128, nullptr, TC4, N4);
    CONV(64,0,64,0, TC4, nullptr, nbr4,  W64+4*S64,   bn64+5*128, nullptr, X4,  N4);
    // ---------------- bottleneck ----------------
    CONV(64,0,64,0, X4,  nullptr, nbr4,  W64+5*S64,   bn64+6*128, nullptr, TB4, N4);
    CONV(64,0,64,1, TB4, nullptr, nbr4,  W64+6*S64,   bn64+7*128, X4,      TC4, N4);
    CONV(64,64,64,2, X4, TC4,     nbr4,  W12864+0*S12864, bn64+11*128, nullptr, TB4, N4);
    // ---------------- decoder: 4 -> 3 ----------------
    CONV(64,0,64,0, TB4, nullptr, nbri4, W64+7*S64,   bn64+8*128, nullptr, TU3, N3);
    CONV(64,0,64,0, X3,  nullptr, nbr3,  W64+8*S64,   bn64+9*128, nullptr, TB3, N3);
    CONV(64,0,64,1, TB3, nullptr, nbr3,  W64+9*S64,   bn64+10*128, X3,     TC3, N3);
    CONV(64,64,64,2, TU3, TC3,    nbr3,  W12864+1*S12864, bn64+12*128, nullptr, TB3, N3);
    // ---------------- decoder: 3 -> 2 ----------------
    CONV(64,0,32,0, TB3, nullptr, nbri3, W6432+0*S6432, bn32+11*64, nullptr, TU2, N2);
    CONV(32,0,32,0, X2,  nullptr, nbr2,  W32+4*S32,   bn32+5*64,  nullptr, TB2, N2);
    CONV(32,0,32,1, TB2, nullptr, nbr2,  W32+5*S32,   bn32+6*64,  X2,      TC2, N2);
    CONV(32,32,32,2, TU2, TC2,    nbr2,  W6432+1*S6432, bn32+12*64, nullptr, TB2, N2);
    // ---------------- decoder: 2 -> 1 ----------------
    CONV(32,0,32,0, TB2, nullptr, nbri2, W32+6*S32,   bn32+7*64,  nullptr, TU1, N1);
    CONV(32,0,32,0, X1,  nullptr, nbr1,  W32+7*S32,   bn32+8*64,  nullptr, TA,  N1);
    CONV(32,0,32,1, TA,  nullptr, nbr1,  W32+8*S32,   bn32+9*64,  X1,      TA2, N1);
    CONV(32,32,32,2, TU1, TA2,    nbr1,  W6432+2*S6432, bn32+13*64, nullptr, TA,  N1);
    // ---------------- head ----------------
    CONV(32,0,32,0, TA,  nullptr, nbr1,  W32+9*S32,   bn32+10*64, nullptr, OUT, N1);
#undef CONV
}